// Round 1
// baseline (2219.501 us; speedup 1.0000x reference)
//
#include <hip/hip_runtime.h>
#include <hip/hip_bf16.h>
#include <math.h>

// Problem constants (B,T,D,H from reference)
#define B_ 2
#define T_ 2048
#define D_ 1024
#define H_ 16
#define DH_ 64
#define NEGV -65504.0f
#define SCALE 0.03125f   // 1/sqrt(1024)

// ---------------------------------------------------------------------------
// fp32 tiled GEMM: C[M,N] = X[M,K] @ W[K,N] + bias[N]
// 64x64 tile, K-tile 16, 256 threads, 4x4 register blocking per thread.
// ---------------------------------------------------------------------------
__global__ __launch_bounds__(256) void gemm_bias_f32(
    const float* __restrict__ X, const float* __restrict__ W,
    const float* __restrict__ bias, float* __restrict__ C,
    int M, int N, int K) {
  __shared__ float As[16][65];  // As[k][m]  (+1 pad: write/read <=2-way)
  __shared__ float Bs[16][65];  // Bs[k][n]

  const int tid = threadIdx.x;
  const int tx = tid & 15;   // col group (0..15)
  const int ty = tid >> 4;   // row group (0..15)
  const int row0 = blockIdx.y * 64;
  const int col0 = blockIdx.x * 64;

  float acc[4][4];
#pragma unroll
  for (int i = 0; i < 4; ++i)
#pragma unroll
    for (int j = 0; j < 4; ++j) acc[i][j] = 0.f;

  for (int k0 = 0; k0 < K; k0 += 16) {
    // A tile: lane reads 16 consecutive k per row chunk (coalesced 64B segs)
    {
      const int k = tid & 15;
      const int mb = tid >> 4;
#pragma unroll
      for (int i = 0; i < 4; ++i) {
        const int m = mb + 16 * i;
        As[k][m] = X[(size_t)(row0 + m) * K + (k0 + k)];
      }
    }
    // B tile: 64 consecutive n per k row (fully coalesced 256B)
    {
      const int n = tid & 63;
      const int kb = tid >> 6;
#pragma unroll
      for (int kk = 0; kk < 4; ++kk) {
        const int k = kb * 4 + kk;
        Bs[k][n] = W[(size_t)(k0 + k) * N + (col0 + n)];
      }
    }
    __syncthreads();
#pragma unroll
    for (int k = 0; k < 16; ++k) {
      float a[4], b[4];
#pragma unroll
      for (int i = 0; i < 4; ++i) a[i] = As[k][ty * 4 + i];
#pragma unroll
      for (int j = 0; j < 4; ++j) b[j] = Bs[k][tx * 4 + j];
#pragma unroll
      for (int i = 0; i < 4; ++i)
#pragma unroll
        for (int j = 0; j < 4; ++j) acc[i][j] += a[i] * b[j];
    }
    __syncthreads();
  }

#pragma unroll
  for (int i = 0; i < 4; ++i) {
    const int r = row0 + ty * 4 + i;
#pragma unroll
    for (int j = 0; j < 4; ++j) {
      const int c = col0 + tx * 4 + j;
      C[(size_t)r * N + c] = acc[i][j] + bias[c];
    }
  }
}

// ---------------------------------------------------------------------------
// Flash-style fp32 attention over projected qh/kh/vh laid out (B, T, H*DH).
// Grid: (T/64, B*H). Block 256 threads: thread t -> q-row r=t>>2, dim-group
// g=t&3 (dims [16g,16g+16)). Online softmax with per-row (m,l) replicated in
// the 4 consecutive lanes of a row (cross-g reduce via __shfl_xor 1,2).
// Key mask applied as score := NEGV (matches reference jnp.where semantics,
// including the all-masked-row uniform case).
// ---------------------------------------------------------------------------
__global__ __launch_bounds__(256) void flash_attn_f32(
    const float* __restrict__ qh, const float* __restrict__ kh,
    const float* __restrict__ vh, const int* __restrict__ mask,
    float* __restrict__ out) {
  const int qt = blockIdx.x;        // query tile (0..T/64)
  const int bh = blockIdx.y;        // 0..B*H
  const int b = bh / H_;
  const int h = bh % H_;

  __shared__ float Qs[64][65];
  __shared__ float Ks[64][65];
  __shared__ float Vs[64][65];
  __shared__ float Ps[64][65];
  __shared__ int   mk[64];

  const int tid = threadIdx.x;
  const int r = tid >> 2;   // q row in tile
  const int g = tid & 3;    // dim group

  const size_t base_q = ((size_t)b * T_ + (size_t)qt * 64) * D_ + (size_t)h * DH_;
  const size_t base_kv0 = (size_t)b * T_ * D_ + (size_t)h * DH_;

  // Load Q tile (coalesced: 64 consecutive dims per row)
#pragma unroll
  for (int i = 0; i < 16; ++i) {
    const int idx = tid + 256 * i;
    const int jr = idx >> 6;
    const int d = idx & 63;
    Qs[jr][d] = qh[base_q + (size_t)jr * D_ + d];
  }

  float m_r = -INFINITY;
  float l_r = 0.f;
  float o[16];
#pragma unroll
  for (int dd = 0; dd < 16; ++dd) o[dd] = 0.f;

  for (int kt = 0; kt < T_ / 64; ++kt) {
    // ---- load K/V tile + mask ----
    const size_t base_kv = base_kv0 + (size_t)kt * 64 * D_;
#pragma unroll
    for (int i = 0; i < 16; ++i) {
      const int idx = tid + 256 * i;
      const int jr = idx >> 6;
      const int d = idx & 63;
      Ks[jr][d] = kh[base_kv + (size_t)jr * D_ + d];
      Vs[jr][d] = vh[base_kv + (size_t)jr * D_ + d];
    }
    if (tid < 64) mk[tid] = mask[b * T_ + kt * 64 + tid];
    __syncthreads();

    // ---- scores for this thread's 16 keys (j = g + 4*jj) ----
    float s[16];
#pragma unroll
    for (int jj = 0; jj < 16; ++jj) s[jj] = 0.f;
#pragma unroll 4
    for (int d = 0; d < 64; ++d) {
      const float qv = Qs[r][d];
#pragma unroll
      for (int jj = 0; jj < 16; ++jj) s[jj] += qv * Ks[g + 4 * jj][d];
    }

    float tmax = -INFINITY;
#pragma unroll
    for (int jj = 0; jj < 16; ++jj) {
      const float v = (mk[g + 4 * jj] != 0) ? s[jj] * SCALE : NEGV;
      s[jj] = v;
      tmax = fmaxf(tmax, v);
    }
    // cross-g row max (lanes 4r..4r+3 are consecutive in one wave)
    tmax = fmaxf(tmax, __shfl_xor(tmax, 1));
    tmax = fmaxf(tmax, __shfl_xor(tmax, 2));

    const float newm = fmaxf(m_r, tmax);            // finite (>= NEGV)
    const float alpha = __expf(m_r - newm);          // first tile: exp(-inf)=0
    float psum = 0.f;
#pragma unroll
    for (int jj = 0; jj < 16; ++jj) {
      const float p = __expf(s[jj] - newm);
      Ps[r][g + 4 * jj] = p;
      psum += p;
    }
    psum += __shfl_xor(psum, 1);
    psum += __shfl_xor(psum, 2);
    l_r = l_r * alpha + psum;
    m_r = newm;
#pragma unroll
    for (int dd = 0; dd < 16; ++dd) o[dd] *= alpha;
    __syncthreads();

    // ---- PV: o[dd] += sum_j P[r][j] * V[j][16g+dd] ----
#pragma unroll 4
    for (int j = 0; j < 64; ++j) {
      const float p = Ps[r][j];
#pragma unroll
      for (int dd = 0; dd < 16; ++dd) o[dd] += p * Vs[j][g * 16 + dd];
    }
    __syncthreads();  // protect Ks/Vs/Ps before next tile's overwrite
  }

  const float inv = 1.f / l_r;  // l_r >= 1 always (see mask analysis)
  const size_t ob = base_q + (size_t)r * D_ + g * 16;
#pragma unroll
  for (int dd = 0; dd < 16; ++dd) out[ob + dd] = o[dd] * inv;
}

// ---------------------------------------------------------------------------
// Launch
// ---------------------------------------------------------------------------
extern "C" void kernel_launch(void* const* d_in, const int* in_sizes, int n_in,
                              void* d_out, int out_size, void* d_ws, size_t ws_size,
                              hipStream_t stream) {
  const float* q  = (const float*)d_in[0];
  const float* k  = (const float*)d_in[1];
  const float* v  = (const float*)d_in[2];
  const int* mask = (const int*)d_in[3];
  const float* Wq = (const float*)d_in[4];
  const float* bq = (const float*)d_in[5];
  const float* Wk = (const float*)d_in[6];
  const float* bk = (const float*)d_in[7];
  const float* Wv = (const float*)d_in[8];
  const float* bv = (const float*)d_in[9];
  const float* Wo = (const float*)d_in[10];
  const float* bo = (const float*)d_in[11];
  float* out = (float*)d_out;

  // Workspace layout (fp32): qh | kh | vh | o  (4 x 16 MB = 64 MB)
  const size_t NELE = (size_t)B_ * T_ * D_;  // 4,194,304
  float* qh  = (float*)d_ws;
  float* kh  = qh + NELE;
  float* vh  = kh + NELE;
  float* oat = vh + NELE;

  const int M = B_ * T_;  // 4096
  dim3 blk(256);
  dim3 ggrid(D_ / 64, M / 64);  // 16 x 64

  gemm_bias_f32<<<ggrid, blk, 0, stream>>>(q, Wq, bq, qh, M, D_, D_);
  gemm_bias_f32<<<ggrid, blk, 0, stream>>>(k, Wk, bk, kh, M, D_, D_);
  gemm_bias_f32<<<ggrid, blk, 0, stream>>>(v, Wv, bv, vh, M, D_, D_);

  dim3 agrid(T_ / 64, B_ * H_);  // 32 x 32
  flash_attn_f32<<<agrid, blk, 0, stream>>>(qh, kh, vh, mask, oat);

  gemm_bias_f32<<<ggrid, blk, 0, stream>>>(oat, Wo, bo, out, M, D_, D_);
}

// Round 2
// 412.460 us; speedup vs baseline: 5.3811x; 5.3811x over previous
//
#include <hip/hip_runtime.h>
#include <hip/hip_bf16.h>
#include <math.h>

#define B_ 2
#define T_ 2048
#define D_ 1024
#define H_ 16
#define NEGV -65504.0f
#define SCALE 0.03125f   // 1/sqrt(1024)

typedef _Float16 f16;
using f16x8 = __attribute__((ext_vector_type(8))) _Float16;
using f32x4 = __attribute__((ext_vector_type(4))) float;

// ---------------------------------------------------------------------------
// MFMA GEMM: C[M,N] = X[M,K] @ W[K,N] + bias.  X is fp32 (XBYTES=4, inline
// cvt) or fp16 (XBYTES=2). W fp32 (inline cvt). Out OT (f16 or float).
// 128x128 tile, BK=32, 256 thr = 4 waves (2x2), each wave 64x64 (4x4 frags).
// LDS rows padded to 40 f16 (80 B = 5*16B) -> b128 frag access is 2 lanes per
// 4-bank group (free). Global->reg->LDS software pipeline.
// ---------------------------------------------------------------------------
template <int XBYTES, typename OT>
__global__ __launch_bounds__(256) void gemm_mfma(
    const void* __restrict__ Xv, const float* __restrict__ W,
    const float* __restrict__ bias, OT* __restrict__ C,
    int M, int N, int K) {
  __shared__ f16 As[128][40];  // [m][k]
  __shared__ f16 Bs[128][40];  // [n][k]  (W transposed into n-major)
  const int tid = threadIdx.x;
  const int wave = tid >> 6, lane = tid & 63;
  const int quad = lane >> 4, l16 = lane & 15;
  const int wm = wave & 1, wn = wave >> 1;
  const int m0 = blockIdx.y * 128, n0 = blockIdx.x * 128;

  f32x4 acc[4][4] = {};  // [tm][tn]

  const int ar = tid >> 1;             // A row 0..127
  const int ak = (tid & 1) * 16;       // A k-half
  const int bn = (tid & 63) + 64 * (tid >> 7);  // B n 0..127
  const int bk = ((tid >> 6) & 1) * 16;         // B k-half

  f16 aregs[16];
  f16 bregs[16];

  auto load_tile = [&](int k0) {
    if constexpr (XBYTES == 4) {
      const float* X = (const float*)Xv;
      const float4* src = (const float4*)(X + (size_t)(m0 + ar) * K + k0 + ak);
#pragma unroll
      for (int i = 0; i < 4; ++i) {
        float4 v = src[i];
        aregs[4 * i + 0] = (f16)v.x; aregs[4 * i + 1] = (f16)v.y;
        aregs[4 * i + 2] = (f16)v.z; aregs[4 * i + 3] = (f16)v.w;
      }
    } else {
      const f16* X = (const f16*)Xv;
      const f16x8* src = (const f16x8*)(X + (size_t)(m0 + ar) * K + k0 + ak);
      *(f16x8*)&aregs[0] = src[0];
      *(f16x8*)&aregs[8] = src[1];
    }
#pragma unroll
    for (int kk = 0; kk < 16; ++kk)   // each instr: 64 consecutive n -> coalesced
      bregs[kk] = (f16)W[(size_t)(k0 + bk + kk) * N + (n0 + bn)];
  };

  load_tile(0);
  const int NK = K >> 5;
  for (int kt = 0; kt < NK; ++kt) {
    *(f16x8*)&As[ar][ak]     = *(f16x8*)&aregs[0];
    *(f16x8*)&As[ar][ak + 8] = *(f16x8*)&aregs[8];
    *(f16x8*)&Bs[bn][bk]     = *(f16x8*)&bregs[0];
    *(f16x8*)&Bs[bn][bk + 8] = *(f16x8*)&bregs[8];
    __syncthreads();
    if (kt + 1 < NK) load_tile(32 * (kt + 1));  // prefetch overlaps compute

    f16x8 af[4], bf[4];
#pragma unroll
    for (int t = 0; t < 4; ++t)
      af[t] = *(const f16x8*)&As[64 * wm + 16 * t + l16][8 * quad];
#pragma unroll
    for (int t = 0; t < 4; ++t)
      bf[t] = *(const f16x8*)&Bs[64 * wn + 16 * t + l16][8 * quad];
#pragma unroll
    for (int i = 0; i < 4; ++i)
#pragma unroll
      for (int j = 0; j < 4; ++j)
        acc[i][j] = __builtin_amdgcn_mfma_f32_16x16x32_f16(af[i], bf[j], acc[i][j], 0, 0, 0);
    __syncthreads();
  }

  // epilogue: C/D layout col=l16, row=4*quad+reg
  const int cm = m0 + 64 * wm + 4 * quad;
  const int cn = n0 + 64 * wn + l16;
#pragma unroll
  for (int tn = 0; tn < 4; ++tn) {
    const float bv = bias[cn + 16 * tn];
#pragma unroll
    for (int tm = 0; tm < 4; ++tm) {
#pragma unroll
      for (int r = 0; r < 4; ++r) {
        float v = acc[tm][tn][r] + bv;
        C[(size_t)(cm + 16 * tm + r) * N + cn + 16 * tn] = (OT)v;
      }
    }
  }
}

// ---------------------------------------------------------------------------
// V transpose: vh (B,T,D) f16 -> vhT (B,H,DH,T) f16 so attention's PV
// B-operand reads are contiguous. 64x64 LDS tile per (b,h,ttile); gather
// order rotated per-lane to spread LDS banks.
// ---------------------------------------------------------------------------
__global__ __launch_bounds__(256) void transpose_v(
    const f16* __restrict__ vh, f16* __restrict__ vhT) {
  __shared__ f16 t[64][72];
  const int tt = blockIdx.x, bh = blockIdx.y;
  const int b = bh >> 4, h = bh & 15;
  const int tid = threadIdx.x;
  const int r = tid >> 2, cq = 16 * (tid & 3);

  const uint4* src = (const uint4*)(vh + ((size_t)(b * T_ + tt * 64 + r)) * D_ + h * 64 + cq);
  *(uint4*)&t[r][cq]     = src[0];
  *(uint4*)&t[r][cq + 8] = src[1];
  __syncthreads();

  f16 tmp[16];
#pragma unroll
  for (int xx = 0; xx < 16; ++xx) {
    int x = (xx + r) & 15;
    tmp[x] = t[cq + x][r];   // column gather, rotated
  }
  f16* dst = vhT + ((size_t)bh * 64 + r) * T_ + tt * 64 + cq;
  *(uint4*)&dst[0] = *(uint4*)&tmp[0];
  *(uint4*)&dst[8] = *(uint4*)&tmp[8];
}

// ---------------------------------------------------------------------------
// MFMA flash attention. Grid (T/64, B*H), 256 thr = 4 waves; wave w owns
// q-rows w*16..w*16+15 of the 64-row tile. Per 64-key tile: S=Q K^T (MFMA),
// scale+mask->NEGV, online softmax (row stats via shfl_xor over 16 lanes),
// P -> wave-private LDS (C-layout write, A-layout b128 read), O += P V (MFMA,
// V pre-transposed). fp32 stats/accumulators; fp16 operands.
// ---------------------------------------------------------------------------
__global__ __launch_bounds__(256) void attn_mfma(
    const f16* __restrict__ qh, const f16* __restrict__ kh,
    const f16* __restrict__ vhT, const int* __restrict__ mask,
    f16* __restrict__ oat) {
  __shared__ f16 Qs[64][72];
  __shared__ f16 Ks[64][72];   // [key][dh]
  __shared__ f16 Vt[64][72];   // [dh][key]
  __shared__ f16 Ps[4][16][72];  // per-wave P strip [qrow][key]
  __shared__ int mk[64];

  const int qt = blockIdx.x, bh = blockIdx.y;
  const int b = bh >> 4, h = bh & 15;
  const int tid = threadIdx.x;
  const int wave = tid >> 6, lane = tid & 63;
  const int quad = lane >> 4, l16 = lane & 15;
  const int sr = tid >> 2, sq = 16 * (tid & 3);

  {  // stage Q once
    const uint4* src = (const uint4*)(qh + ((size_t)(b * T_ + qt * 64 + sr)) * D_ + h * 64 + sq);
    *(uint4*)&Qs[sr][sq]     = src[0];
    *(uint4*)&Qs[sr][sq + 8] = src[1];
  }
  __syncthreads();
  const f16x8 qf0 = *(const f16x8*)&Qs[wave * 16 + l16][quad * 8];
  const f16x8 qf1 = *(const f16x8*)&Qs[wave * 16 + l16][32 + quad * 8];

  float m_r[4], l_r[4];
  f32x4 o[4] = {};
#pragma unroll
  for (int r = 0; r < 4; ++r) { m_r[r] = -INFINITY; l_r[r] = 0.f; }

  const f16* kbase = kh + (size_t)b * T_ * D_ + h * 64;
  const f16* vbase = vhT + ((size_t)bh * 64 + sr) * T_;

  uint4 kr0, kr1, vr0, vr1;
  int mreg = 0;
  auto load_kv = [&](int kt) {
    const uint4* ks = (const uint4*)(kbase + (size_t)(kt * 64 + sr) * D_ + sq);
    kr0 = ks[0]; kr1 = ks[1];
    const uint4* vs = (const uint4*)(vbase + kt * 64 + sq);
    vr0 = vs[0]; vr1 = vs[1];
    if (tid < 64) mreg = mask[b * T_ + kt * 64 + tid];
  };
  load_kv(0);

  for (int kt = 0; kt < T_ / 64; ++kt) {
    *(uint4*)&Ks[sr][sq]     = kr0;
    *(uint4*)&Ks[sr][sq + 8] = kr1;
    *(uint4*)&Vt[sr][sq]     = vr0;
    *(uint4*)&Vt[sr][sq + 8] = vr1;
    if (tid < 64) mk[tid] = mreg;
    __syncthreads();
    if (kt + 1 < T_ / 64) load_kv(kt + 1);  // prefetch

    // ---- S = Q K^T ----
    f32x4 sv[4];
#pragma unroll
    for (int tn = 0; tn < 4; ++tn) {
      f16x8 kf0 = *(const f16x8*)&Ks[16 * tn + l16][quad * 8];
      f16x8 kf1 = *(const f16x8*)&Ks[16 * tn + l16][32 + quad * 8];
      f32x4 s = {0.f, 0.f, 0.f, 0.f};
      s = __builtin_amdgcn_mfma_f32_16x16x32_f16(qf0, kf0, s, 0, 0, 0);
      s = __builtin_amdgcn_mfma_f32_16x16x32_f16(qf1, kf1, s, 0, 0, 0);
      sv[tn] = s;
    }
    int mv[4];
#pragma unroll
    for (int tn = 0; tn < 4; ++tn) mv[tn] = mk[16 * tn + l16];

    // ---- online softmax per row r (row = 4*quad + r) ----
    float al[4];
#pragma unroll
    for (int r = 0; r < 4; ++r) {
      float s0 = mv[0] ? sv[0][r] * SCALE : NEGV;
      float s1 = mv[1] ? sv[1][r] * SCALE : NEGV;
      float s2 = mv[2] ? sv[2][r] * SCALE : NEGV;
      float s3 = mv[3] ? sv[3][r] * SCALE : NEGV;
      float mx = fmaxf(fmaxf(s0, s1), fmaxf(s2, s3));
      mx = fmaxf(mx, __shfl_xor(mx, 1));
      mx = fmaxf(mx, __shfl_xor(mx, 2));
      mx = fmaxf(mx, __shfl_xor(mx, 4));
      mx = fmaxf(mx, __shfl_xor(mx, 8));
      const float nm = fmaxf(m_r[r], mx);
      al[r] = __expf(m_r[r] - nm);       // first tile: exp(-inf)=0
      float p0 = __expf(s0 - nm), p1 = __expf(s1 - nm);
      float p2 = __expf(s2 - nm), p3 = __expf(s3 - nm);
      Ps[wave][4 * quad + r][l16]      = (f16)p0;
      Ps[wave][4 * quad + r][16 + l16] = (f16)p1;
      Ps[wave][4 * quad + r][32 + l16] = (f16)p2;
      Ps[wave][4 * quad + r][48 + l16] = (f16)p3;
      float sum = p0 + p1 + p2 + p3;
      sum += __shfl_xor(sum, 1);
      sum += __shfl_xor(sum, 2);
      sum += __shfl_xor(sum, 4);
      sum += __shfl_xor(sum, 8);
      l_r[r] = l_r[r] * al[r] + sum;
      m_r[r] = nm;
    }
#pragma unroll
    for (int on = 0; on < 4; ++on)
#pragma unroll
      for (int r = 0; r < 4; ++r) o[on][r] *= al[r];

    // ---- O += P V  (P via LDS round-trip; same-wave DS ops are in-order) ----
    f16x8 pf0 = *(const f16x8*)&Ps[wave][l16][quad * 8];
    f16x8 pf1 = *(const f16x8*)&Ps[wave][l16][32 + quad * 8];
#pragma unroll
    for (int on = 0; on < 4; ++on) {
      f16x8 vf0 = *(const f16x8*)&Vt[16 * on + l16][quad * 8];
      f16x8 vf1 = *(const f16x8*)&Vt[16 * on + l16][32 + quad * 8];
      o[on] = __builtin_amdgcn_mfma_f32_16x16x32_f16(pf0, vf0, o[on], 0, 0, 0);
      o[on] = __builtin_amdgcn_mfma_f32_16x16x32_f16(pf1, vf1, o[on], 0, 0, 0);
    }
    __syncthreads();
  }

  const size_t orow = (size_t)(b * T_ + qt * 64 + wave * 16 + 4 * quad);
#pragma unroll
  for (int r = 0; r < 4; ++r) {
    const float inv = 1.f / l_r[r];
#pragma unroll
    for (int on = 0; on < 4; ++on)
      oat[(orow + r) * D_ + h * 64 + 16 * on + l16] = (f16)(o[on][r] * inv);
  }
}

// ---------------------------------------------------------------------------
extern "C" void kernel_launch(void* const* d_in, const int* in_sizes, int n_in,
                              void* d_out, int out_size, void* d_ws, size_t ws_size,
                              hipStream_t stream) {
  const float* q  = (const float*)d_in[0];
  const float* k  = (const float*)d_in[1];
  const float* v  = (const float*)d_in[2];
  const int* mask = (const int*)d_in[3];
  const float* Wq = (const float*)d_in[4];
  const float* bq = (const float*)d_in[5];
  const float* Wk = (const float*)d_in[6];
  const float* bk = (const float*)d_in[7];
  const float* Wv = (const float*)d_in[8];
  const float* bv = (const float*)d_in[9];
  const float* Wo = (const float*)d_in[10];
  const float* bo = (const float*)d_in[11];
  float* out = (float*)d_out;

  const size_t NELE = (size_t)B_ * T_ * D_;  // 4,194,304
  f16* qh  = (f16*)d_ws;
  f16* kh  = qh + NELE;
  f16* vh  = kh + NELE;
  f16* vhT = vh + NELE;
  f16* oat = vhT + NELE;   // total 40 MB

  const int M = B_ * T_;  // 4096
  dim3 blk(256);
  dim3 ggrid(D_ / 128, M / 128);  // (8, 32)

  gemm_mfma<4, f16><<<ggrid, blk, 0, stream>>>(q, Wq, bq, qh, M, D_, D_);
  gemm_mfma<4, f16><<<ggrid, blk, 0, stream>>>(k, Wk, bk, kh, M, D_, D_);
  gemm_mfma<4, f16><<<ggrid, blk, 0, stream>>>(v, Wv, bv, vh, M, D_, D_);

  dim3 tgrid(T_ / 64, B_ * H_);  // (32, 32)
  transpose_v<<<tgrid, blk, 0, stream>>>(vh, vhT);

  attn_mfma<<<tgrid, blk, 0, stream>>>(qh, kh, vhT, mask, oat);

  gemm_mfma<2, float><<<ggrid, blk, 0, stream>>>(oat, Wo, bo, out, M, D_, D_);
}

// Round 3
// 290.452 us; speedup vs baseline: 7.6415x; 1.4201x over previous
//
#include <hip/hip_runtime.h>
#include <hip/hip_bf16.h>
#include <math.h>

#define B_ 2
#define T_ 2048
#define D_ 1024
#define H_ 16
#define SCALE 0.03125f            // 1/sqrt(1024)
#define QSCALE (0.03125f * 1.44269504088896f)  // fold log2e: exp2(s') == exp(s*SCALE)

typedef _Float16 f16;
using f16x4 = __attribute__((ext_vector_type(4))) _Float16;
using f16x8 = __attribute__((ext_vector_type(8))) _Float16;
using f32x4 = __attribute__((ext_vector_type(4))) float;

__device__ __forceinline__ void gl16(const void* g, void* l) {
  __builtin_amdgcn_global_load_lds(
      (__attribute__((address_space(1))) void*)g,
      (__attribute__((address_space(3))) void*)l, 16, 0, 0);
}

// ---------------------------------------------------------------------------
// cvt_x: fp32 -> f16, 3 tensors batched on blockIdx.y
// ---------------------------------------------------------------------------
__global__ __launch_bounds__(256) void cvt_x(
    const float* __restrict__ q, const float* __restrict__ k,
    const float* __restrict__ v, f16* __restrict__ dst) {
  const int z = blockIdx.y;
  const float* src = (z == 0) ? q : (z == 1) ? k : v;
  const size_t i = ((size_t)blockIdx.x * 256 + threadIdx.x) * 8;
  float4 a = *(const float4*)(src + i);
  float4 b = *(const float4*)(src + i + 4);
  f16x8 o;
  o[0] = (f16)a.x; o[1] = (f16)a.y; o[2] = (f16)a.z; o[3] = (f16)a.w;
  o[4] = (f16)b.x; o[5] = (f16)b.y; o[6] = (f16)b.z; o[7] = (f16)b.w;
  *(f16x8*)(dst + (size_t)z * 4194304 + i) = o;
}

// ---------------------------------------------------------------------------
// cvt_w: W [K][N] fp32 -> Wt [N][K] f16 (transpose+cvt), 4 matrices on z
// ---------------------------------------------------------------------------
__global__ __launch_bounds__(256) void cvt_w(
    const float* __restrict__ Wq, const float* __restrict__ Wk,
    const float* __restrict__ Wv, const float* __restrict__ Wo,
    f16* __restrict__ Wt) {
  const int z = blockIdx.z;
  const float* W = (z == 0) ? Wq : (z == 1) ? Wk : (z == 2) ? Wv : Wo;
  const int k0 = blockIdx.x * 64, n0 = blockIdx.y * 64;
  __shared__ float t[64][65];
  const int tid = threadIdx.x;
  const int r = tid >> 2, c0 = (tid & 3) * 16;
#pragma unroll
  for (int i = 0; i < 4; ++i)
    *(float4*)&t[r][c0 + 4 * i] = *(const float4*)&W[(size_t)(k0 + r) * 1024 + n0 + c0 + 4 * i];
  __syncthreads();
  f16 tmp[16];
#pragma unroll
  for (int i = 0; i < 16; ++i) tmp[i] = (f16)t[c0 + i][r];
  f16* dst = Wt + (size_t)z * 1048576 + (size_t)(n0 + r) * 1024 + k0 + c0;
  *(f16x8*)dst = *(f16x8*)&tmp[0];
  *(f16x8*)(dst + 8) = *(f16x8*)&tmp[8];
}

// ---------------------------------------------------------------------------
// pack_bias: bq|bk|bv|bo contiguous
// ---------------------------------------------------------------------------
__global__ __launch_bounds__(256) void pack_bias(
    const float* __restrict__ bq, const float* __restrict__ bk,
    const float* __restrict__ bv, const float* __restrict__ bo,
    float* __restrict__ out) {
  const int i = blockIdx.x * 256 + threadIdx.x;  // 0..4095
  const int z = i >> 10;
  const float* s = (z == 0) ? bq : (z == 1) ? bk : (z == 2) ? bv : bo;
  out[i] = s[i & 1023];
}

// ---------------------------------------------------------------------------
// m97-style GEMM: C[M,N] = X[M,K] @ Wt[N,K]^T, f16 in, 128x128 tile, BK=32,
// global_load_lds width-16 staging, 4 waves (2x2) x 64x64, 4x4 frags.
// z batches independent (X, Wt, bias, C) problems (QKV). scale applied when
// z==0 (folds attention score scale + log2e into qh).
// ---------------------------------------------------------------------------
template <typename OT>
__global__ __launch_bounds__(256) void gemm_bt(
    const f16* __restrict__ Xb, const f16* __restrict__ Wtb,
    const float* __restrict__ biasb, OT* __restrict__ Cb,
    int M, int N, int K, float qscale) {
  __shared__ __align__(16) f16 As[128 * 32];
  __shared__ __align__(16) f16 Bs[128 * 32];
  const int z = blockIdx.z;
  const f16* X  = Xb  + (size_t)z * M * K;
  const f16* Wt = Wtb + (size_t)z * N * K;
  const float* bias = biasb + (size_t)z * N;
  OT* C = Cb + (size_t)z * M * N;
  const float scl = (z == 0) ? qscale : 1.f;

  const int tid = threadIdx.x;
  const int wave = tid >> 6, lane = tid & 63;
  const int quad = lane >> 4, l16 = lane & 15;
  const int wm = wave & 1, wn = wave >> 1;
  const int m0 = blockIdx.y * 128, n0 = blockIdx.x * 128;

  f32x4 acc[4][4] = {};

  // staging: instr j in {0,1}: row = wave*16 + (lane>>2) + 64*j, k = (lane&3)*8
  const f16* asrc = X  + (size_t)(m0 + wave * 16 + (lane >> 2)) * K + (lane & 3) * 8;
  const f16* bsrc = Wt + (size_t)(n0 + wave * 16 + (lane >> 2)) * K + (lane & 3) * 8;
  char* aldst = (char*)As + tid * 16;
  char* bldst = (char*)Bs + tid * 16;
  const size_t rstep = (size_t)64 * K;

  const int NK = K >> 5;
  for (int kt = 0; kt < NK; ++kt) {
    if (kt) __syncthreads();
    gl16(asrc, aldst);
    gl16(asrc + rstep, aldst + 4096);
    gl16(bsrc, bldst);
    gl16(bsrc + rstep, bldst + 4096);
    asrc += 32; bsrc += 32;
    __syncthreads();

    f16x8 af[4], bf[4];
#pragma unroll
    for (int t = 0; t < 4; ++t)
      af[t] = *(const f16x8*)&As[(64 * wm + 16 * t + l16) * 32 + quad * 8];
#pragma unroll
    for (int t = 0; t < 4; ++t)
      bf[t] = *(const f16x8*)&Bs[(64 * wn + 16 * t + l16) * 32 + quad * 8];
#pragma unroll
    for (int i = 0; i < 4; ++i)
#pragma unroll
      for (int j = 0; j < 4; ++j)
        acc[i][j] = __builtin_amdgcn_mfma_f32_16x16x32_f16(af[i], bf[j], acc[i][j], 0, 0, 0);
  }

  const int cm = m0 + 64 * wm + 4 * quad;
  const int cn = n0 + 64 * wn + l16;
#pragma unroll
  for (int tn = 0; tn < 4; ++tn) {
    const float bv = bias[cn + 16 * tn];
#pragma unroll
    for (int tm = 0; tm < 4; ++tm)
#pragma unroll
      for (int r = 0; r < 4; ++r)
        C[(size_t)(cm + 16 * tm + r) * N + cn + 16 * tn] = (OT)((acc[tm][tn][r] + bv) * scl);
  }
}

// ---------------------------------------------------------------------------
// V transpose: vh (B,T,D) f16 -> vhT (B,H,DH,T) f16
// ---------------------------------------------------------------------------
__global__ __launch_bounds__(256) void transpose_v(
    const f16* __restrict__ vh, f16* __restrict__ vhT) {
  __shared__ f16 t[64][72];
  const int tt = blockIdx.x, bh = blockIdx.y;
  const int b = bh >> 4, h = bh & 15;
  const int tid = threadIdx.x;
  const int r = tid >> 2, cq = 16 * (tid & 3);

  const uint4* src = (const uint4*)(vh + ((size_t)(b * T_ + tt * 64 + r)) * D_ + h * 64 + cq);
  *(uint4*)&t[r][cq]     = src[0];
  *(uint4*)&t[r][cq + 8] = src[1];
  __syncthreads();

  f16 tmp[16];
#pragma unroll
  for (int xx = 0; xx < 16; ++xx) {
    int x = (xx + r) & 15;
    tmp[x] = t[cq + x][r];
  }
  f16* dst = vhT + ((size_t)bh * 64 + r) * T_ + tt * 64 + cq;
  *(uint4*)&dst[0] = *(uint4*)&tmp[0];
  *(uint4*)&dst[8] = *(uint4*)&tmp[8];
}

// ---------------------------------------------------------------------------
// Flash attention, S^T formulation, fixed-max softmax.
// qh is PRE-SCALED by SCALE*log2e, so P = exp2(S) * maskf.
// Wave w owns q-rows w*16..w*16+15; lane's l16 = its q-row for both the S^T
// output (C col) and the PV A-operand (A row) -> P packs as 4x b64, no
// per-tile cross-lane reductions.  l reduced once at the end (quads hold
// disjoint key subsets).
// ---------------------------------------------------------------------------
__global__ __launch_bounds__(256) void attn_mfma(
    const f16* __restrict__ qh, const f16* __restrict__ kh,
    const f16* __restrict__ vhT, const int* __restrict__ mask,
    f16* __restrict__ oat) {
  __shared__ f16 Qs[64][72];
  __shared__ f16 Ks[64][72];     // [key][dh]
  __shared__ f16 Vt[64][72];     // [dh][key]
  __shared__ f16 Ps[4][16][72];  // per-wave [qrow(l16)][key]
  __shared__ float mkf[64];

  const int qt = blockIdx.x, bh = blockIdx.y;
  const int b = bh >> 4, h = bh & 15;
  const int tid = threadIdx.x;
  const int wave = tid >> 6, lane = tid & 63;
  const int quad = lane >> 4, l16 = lane & 15;
  const int sr = tid >> 2, sq = 16 * (tid & 3);

  {  // stage Q once
    const uint4* src = (const uint4*)(qh + ((size_t)(b * T_ + qt * 64 + sr)) * D_ + h * 64 + sq);
    *(uint4*)&Qs[sr][sq]     = src[0];
    *(uint4*)&Qs[sr][sq + 8] = src[1];
  }
  __syncthreads();
  const f16x8 qf0 = *(const f16x8*)&Qs[wave * 16 + l16][quad * 8];
  const f16x8 qf1 = *(const f16x8*)&Qs[wave * 16 + l16][32 + quad * 8];

  float lsum = 0.f;
  f32x4 o[4] = {};

  const f16* kbase = kh + (size_t)b * T_ * D_ + h * 64;
  const f16* vbase = vhT + ((size_t)bh * 64 + sr) * T_;

  uint4 kr0, kr1, vr0, vr1;
  int mreg = 0;
  auto load_kv = [&](int kt) {
    const uint4* ks = (const uint4*)(kbase + (size_t)(kt * 64 + sr) * D_ + sq);
    kr0 = ks[0]; kr1 = ks[1];
    const uint4* vs = (const uint4*)(vbase + kt * 64 + sq);
    vr0 = vs[0]; vr1 = vs[1];
    if (tid < 64) mreg = mask[b * T_ + kt * 64 + tid];
  };
  load_kv(0);

  for (int kt = 0; kt < T_ / 64; ++kt) {
    *(uint4*)&Ks[sr][sq]     = kr0;
    *(uint4*)&Ks[sr][sq + 8] = kr1;
    *(uint4*)&Vt[sr][sq]     = vr0;
    *(uint4*)&Vt[sr][sq + 8] = vr1;
    if (tid < 64) mkf[tid] = (float)mreg;
    __syncthreads();
    if (kt + 1 < T_ / 64) load_kv(kt + 1);  // prefetch next tile into regs

    // ---- S^T = K Q^T : D[m=key][n=qrow] ----
#pragma unroll
    for (int tn = 0; tn < 4; ++tn) {
      f16x8 kf0 = *(const f16x8*)&Ks[16 * tn + l16][quad * 8];
      f16x8 kf1 = *(const f16x8*)&Ks[16 * tn + l16][32 + quad * 8];
      f32x4 s = {0.f, 0.f, 0.f, 0.f};
      s = __builtin_amdgcn_mfma_f32_16x16x32_f16(kf0, qf0, s, 0, 0, 0);
      s = __builtin_amdgcn_mfma_f32_16x16x32_f16(kf1, qf1, s, 0, 0, 0);
      // lane holds S for qrow=l16, keys 16*tn + 4*quad + r
      const float4 mf = *(const float4*)&mkf[16 * tn + 4 * quad];
      f16x4 pk;
      float p0 = exp2f(s[0]) * mf.x;
      float p1 = exp2f(s[1]) * mf.y;
      float p2 = exp2f(s[2]) * mf.z;
      float p3 = exp2f(s[3]) * mf.w;
      lsum += (p0 + p1) + (p2 + p3);
      pk[0] = (f16)p0; pk[1] = (f16)p1; pk[2] = (f16)p2; pk[3] = (f16)p3;
      *(f16x4*)&Ps[wave][l16][16 * tn + 4 * quad] = pk;
    }

    // ---- O += P V  (same-wave LDS round-trip; compiler inserts lgkm waits) ----
    f16x8 pf0 = *(const f16x8*)&Ps[wave][l16][quad * 8];
    f16x8 pf1 = *(const f16x8*)&Ps[wave][l16][32 + quad * 8];
#pragma unroll
    for (int t = 0; t < 4; ++t) {
      f16x8 vf0 = *(const f16x8*)&Vt[16 * t + l16][quad * 8];
      f16x8 vf1 = *(const f16x8*)&Vt[16 * t + l16][32 + quad * 8];
      o[t] = __builtin_amdgcn_mfma_f32_16x16x32_f16(pf0, vf0, o[t], 0, 0, 0);
      o[t] = __builtin_amdgcn_mfma_f32_16x16x32_f16(pf1, vf1, o[t], 0, 0, 0);
    }
    __syncthreads();
  }

  // final l: quads hold disjoint key subsets for qrow=l16
  lsum += __shfl_xor(lsum, 16);
  lsum += __shfl_xor(lsum, 32);
  float inv[4];
#pragma unroll
  for (int r = 0; r < 4; ++r) inv[r] = 1.f / __shfl(lsum, 4 * quad + r);

  // o: lane holds O[qrow=4*quad+r][dh=16*t+l16]
  const size_t orow = (size_t)(b * T_ + qt * 64 + wave * 16 + 4 * quad);
#pragma unroll
  for (int r = 0; r < 4; ++r)
#pragma unroll
    for (int t = 0; t < 4; ++t)
      oat[(orow + r) * D_ + h * 64 + 16 * t + l16] = (f16)(o[t][r] * inv[r]);
}

// ---------------------------------------------------------------------------
extern "C" void kernel_launch(void* const* d_in, const int* in_sizes, int n_in,
                              void* d_out, int out_size, void* d_ws, size_t ws_size,
                              hipStream_t stream) {
  const float* q  = (const float*)d_in[0];
  const float* k  = (const float*)d_in[1];
  const float* v  = (const float*)d_in[2];
  const int* mask = (const int*)d_in[3];
  const float* Wq = (const float*)d_in[4];
  const float* bq = (const float*)d_in[5];
  const float* Wk = (const float*)d_in[6];
  const float* bk = (const float*)d_in[7];
  const float* Wv = (const float*)d_in[8];
  const float* bv = (const float*)d_in[9];
  const float* Wo = (const float*)d_in[10];
  const float* bo = (const float*)d_in[11];
  float* out = (float*)d_out;

  // ws layout (bytes):
  //  A: 0        .. 25165824   xq|xk|xv f16 (3 x 8MB); later vhT @0, oat @8MB
  //  B: 25165824 .. 33554432   Wt f16 [4][1024][1024]
  //  b: 33554432 .. 33570816   bias fp32 [4][1024]
  //  C: 33570816 .. 58736640   qh|kh|vh f16 (3 x 8MB)
  char* ws = (char*)d_ws;
  f16* xqkv  = (f16*)(ws);
  f16* Wt    = (f16*)(ws + 25165824);
  float* bsw = (float*)(ws + 33554432);
  f16* qkvh  = (f16*)(ws + 33570816);
  f16* vhT   = (f16*)(ws);             // aliases xq (dead after QKV gemm)
  f16* oat   = (f16*)(ws + 8388608);   // aliases xk (dead after QKV gemm)

  const int M = B_ * T_;  // 4096
  dim3 blk(256);

  cvt_x<<<dim3(2048, 3), blk, 0, stream>>>(q, k, v, xqkv);
  cvt_w<<<dim3(16, 16, 4), blk, 0, stream>>>(Wq, Wk, Wv, Wo, Wt);
  pack_bias<<<dim3(16), blk, 0, stream>>>(bq, bk, bv, bo, bsw);

  gemm_bt<f16><<<dim3(8, 32, 3), blk, 0, stream>>>(
      xqkv, Wt, bsw, qkvh, M, D_, D_, QSCALE);

  f16* qh = qkvh;
  f16* kh = qkvh + 4194304;
  f16* vh = qkvh + 8388608;

  transpose_v<<<dim3(32, 32), blk, 0, stream>>>(vh, vhT);
  attn_mfma<<<dim3(32, 32), blk, 0, stream>>>(qh, kh, vhT, mask, oat);

  gemm_bt<float><<<dim3(8, 32, 1), blk, 0, stream>>>(
      oat, Wt + 3145728, bsw + 3072, out, M, D_, D_, 1.f);
}

// Round 4
// 247.850 us; speedup vs baseline: 8.9550x; 1.1719x over previous
//
#include <hip/hip_runtime.h>
#include <hip/hip_bf16.h>
#include <math.h>

#define B_ 2
#define T_ 2048
#define D_ 1024
#define H_ 16
#define QSCALE (0.03125f * 1.44269504088896f)  // 1/sqrt(1024) * log2(e)

typedef _Float16 f16;
using f16x4 = __attribute__((ext_vector_type(4))) _Float16;
using f16x8 = __attribute__((ext_vector_type(8))) _Float16;
using f32x4 = __attribute__((ext_vector_type(4))) float;

__device__ __forceinline__ void gl16(const void* g, void* l) {
  __builtin_amdgcn_global_load_lds(
      (__attribute__((address_space(1))) void*)g,
      (__attribute__((address_space(3))) void*)l, 16, 0, 0);
}

// ---------------------------------------------------------------------------
// prep: fused cvt_x (blocks 0..6143) + cvt_w transpose (6144..7167) +
// pack_bias (7168..7183) + mask prefix-scan -> idx/nk (7184..7185)
// ---------------------------------------------------------------------------
__global__ __launch_bounds__(256) void prep(
    const float* __restrict__ q, const float* __restrict__ k,
    const float* __restrict__ v, const int* __restrict__ mask,
    const float* __restrict__ Wq, const float* __restrict__ Wk,
    const float* __restrict__ Wv, const float* __restrict__ Wo,
    const float* __restrict__ bq, const float* __restrict__ bk,
    const float* __restrict__ bv, const float* __restrict__ bo,
    f16* __restrict__ xqkv, f16* __restrict__ Wt, float* __restrict__ bias,
    int* __restrict__ idx, int* __restrict__ nk) {
  __shared__ float sh[64][65];
  const int bid = blockIdx.x;
  const int tid = threadIdx.x;

  if (bid < 6144) {  // ---- cvt_x: fp32 -> f16, 2048 elems/block ----
    const int z = bid / 2048;
    const float* src = (z == 0) ? q : (z == 1) ? k : v;
    const size_t i = ((size_t)(bid % 2048) * 256 + tid) * 8;
    float4 a = *(const float4*)(src + i);
    float4 b = *(const float4*)(src + i + 4);
    f16x8 o;
    o[0] = (f16)a.x; o[1] = (f16)a.y; o[2] = (f16)a.z; o[3] = (f16)a.w;
    o[4] = (f16)b.x; o[5] = (f16)b.y; o[6] = (f16)b.z; o[7] = (f16)b.w;
    *(f16x8*)(xqkv + (size_t)z * 4194304 + i) = o;
  } else if (bid < 7168) {  // ---- cvt_w: W[K][N] fp32 -> Wt[N][K] f16 ----
    const int id = bid - 6144;
    const int z = id >> 8;
    const int k0 = ((id >> 4) & 15) * 64, n0 = (id & 15) * 64;
    const float* W = (z == 0) ? Wq : (z == 1) ? Wk : (z == 2) ? Wv : Wo;
    const int r = tid >> 2, c0 = (tid & 3) * 16;
#pragma unroll
    for (int i = 0; i < 4; ++i)
      *(float4*)&sh[r][c0 + 4 * i] =
          *(const float4*)&W[(size_t)(k0 + r) * 1024 + n0 + c0 + 4 * i];
    __syncthreads();
    f16 tmp[16];
#pragma unroll
    for (int i = 0; i < 16; ++i) tmp[i] = (f16)sh[c0 + i][r];
    f16* dst = Wt + (size_t)z * 1048576 + (size_t)(n0 + r) * 1024 + k0 + c0;
    *(f16x8*)dst = *(f16x8*)&tmp[0];
    *(f16x8*)(dst + 8) = *(f16x8*)&tmp[8];
  } else if (bid < 7184) {  // ---- pack_bias ----
    const int i = (bid - 7168) * 256 + tid;
    const int z = i >> 10;
    const float* s = (z == 0) ? bq : (z == 1) ? bk : (z == 2) ? bv : bo;
    bias[i] = s[i & 1023];
  } else {  // ---- mask scan, one block per batch ----
    const int b = bid - 7184;
    int* cnt = (int*)sh;
    int loc[8];
    int c = 0;
#pragma unroll
    for (int i = 0; i < 8; ++i) {
      loc[i] = mask[b * T_ + tid * 8 + i];
      c += loc[i];
    }
    cnt[tid] = c;
    __syncthreads();
    for (int off = 1; off < 256; off <<= 1) {
      int vsh = (tid >= off) ? cnt[tid - off] : 0;
      __syncthreads();
      cnt[tid] += vsh;
      __syncthreads();
    }
    int pos = cnt[tid] - c;  // exclusive
#pragma unroll
    for (int i = 0; i < 8; ++i)
      if (loc[i]) idx[b * T_ + pos++] = tid * 8 + i;
    if (tid == 255) nk[b] = cnt[255];
  }
}

// ---------------------------------------------------------------------------
// m97-style GEMM: C[M,N] = X[M,K] @ Wt[N,K]^T + bias, f16 in.
// TM x 128 tile, BK=32, global_load_lds width-16 staging, 4 waves (2x2).
// TM=128: wave 64x64 (4x4 frags); TM=64: wave 32x64 (2x4), 2x grid.y.
// z batches independent problems; z==0 applies qscale (attn scale+log2e).
// ---------------------------------------------------------------------------
template <int TM, typename OT>
__global__ __launch_bounds__(256) void gemm_bt(
    const f16* __restrict__ Xb, const f16* __restrict__ Wtb,
    const float* __restrict__ biasb, OT* __restrict__ Cb,
    int M, int N, int K, float qscale) {
  constexpr int FM = TM / 32;  // frags per wave in M: 4 or 2
  __shared__ __align__(16) f16 As[TM * 32];
  __shared__ __align__(16) f16 Bs[128 * 32];
  const int z = blockIdx.z;
  const f16* X  = Xb  + (size_t)z * M * K;
  const f16* Wt = Wtb + (size_t)z * N * K;
  const float* bias = biasb + (size_t)z * N;
  OT* C = Cb + (size_t)z * M * N;
  const float scl = (z == 0) ? qscale : 1.f;

  const int tid = threadIdx.x;
  const int wave = tid >> 6, lane = tid & 63;
  const int quad = lane >> 4, l16 = lane & 15;
  const int wm = wave & 1, wn = wave >> 1;
  const int m0 = blockIdx.y * TM, n0 = blockIdx.x * 128;

  f32x4 acc[FM][4] = {};

  const f16* asrc = X  + (size_t)(m0 + (tid >> 2)) * K + (tid & 3) * 8;
  const f16* bsrc = Wt + (size_t)(n0 + (tid >> 2)) * K + (tid & 3) * 8;
  char* aldst = (char*)As + tid * 16;
  char* bldst = (char*)Bs + tid * 16;
  const size_t rstep = (size_t)64 * K;

  const int NK = K >> 5;
  for (int kt = 0; kt < NK; ++kt) {
    if (kt) __syncthreads();
    gl16(asrc, aldst);
    if constexpr (TM == 128) gl16(asrc + rstep, aldst + 4096);
    gl16(bsrc, bldst);
    gl16(bsrc + rstep, bldst + 4096);
    asrc += 32; bsrc += 32;
    __syncthreads();

    f16x8 af[FM], bf[4];
#pragma unroll
    for (int t = 0; t < FM; ++t)
      af[t] = *(const f16x8*)&As[((TM / 2) * wm + 16 * t + l16) * 32 + quad * 8];
#pragma unroll
    for (int t = 0; t < 4; ++t)
      bf[t] = *(const f16x8*)&Bs[(64 * wn + 16 * t + l16) * 32 + quad * 8];
#pragma unroll
    for (int i = 0; i < FM; ++i)
#pragma unroll
      for (int j = 0; j < 4; ++j)
        acc[i][j] = __builtin_amdgcn_mfma_f32_16x16x32_f16(af[i], bf[j], acc[i][j], 0, 0, 0);
  }

  const int cm = m0 + (TM / 2) * wm + 4 * quad;
  const int cn = n0 + 64 * wn + l16;
#pragma unroll
  for (int tn = 0; tn < 4; ++tn) {
    const float bv = bias[cn + 16 * tn];
#pragma unroll
    for (int tm = 0; tm < FM; ++tm)
#pragma unroll
      for (int r = 0; r < 4; ++r)
        C[(size_t)(cm + 16 * tm + r) * N + cn + 16 * tn] = (OT)((acc[tm][tn][r] + bv) * scl);
  }
}

// ---------------------------------------------------------------------------
// kgather: khc[b][j][:] = kh[b][idx[b][j]][:], zero for j in [nk, nkt*64).
// grid (32, 2); row-contiguous copies (half-block per row).
// ---------------------------------------------------------------------------
__global__ __launch_bounds__(256) void kgather(
    const f16* __restrict__ kh, const int* __restrict__ idx,
    const int* __restrict__ nk, f16* __restrict__ khc) {
  const int b = blockIdx.y;
  const int n = nk[b];
  const int nkt = (n + 63) >> 6;
  if ((int)blockIdx.x >= nkt) return;
  const int j0 = blockIdx.x * 64;
  const int r2 = threadIdx.x >> 7;        // 0/1
  const int col = threadIdx.x & 127;      // 16B chunk
  for (int rr = 0; rr < 32; ++rr) {
    const int j = j0 + rr * 2 + r2;
    uint4 val = {0u, 0u, 0u, 0u};
    if (j < n) {
      const int t = idx[b * T_ + j];
      val = *(const uint4*)(kh + ((size_t)b * T_ + t) * D_ + col * 8);
    }
    *(uint4*)(khc + ((size_t)b * T_ + j) * D_ + col * 8) = val;
  }
}

// ---------------------------------------------------------------------------
// vtrans: gather + transpose V. vhT[bh][dh][j] = vh[b][idx[j]][h*64+dh],
// zeros for pad j. Only tiles < nkt written (attn reads nothing beyond).
// ---------------------------------------------------------------------------
__global__ __launch_bounds__(256) void vtrans(
    const f16* __restrict__ vh, const int* __restrict__ idx,
    const int* __restrict__ nk, f16* __restrict__ vhT) {
  const int tt = blockIdx.x, bh = blockIdx.y;
  const int b = bh >> 4, h = bh & 15;
  const int n = nk[b];
  const int nkt = (n + 63) >> 6;
  if (tt >= nkt) return;
  __shared__ f16 t[64][72];
  const int tid = threadIdx.x;
  const int r = tid >> 2, cq = 16 * (tid & 3);

  const int j = tt * 64 + r;
  uint4 v0 = {0u, 0u, 0u, 0u}, v1 = {0u, 0u, 0u, 0u};
  if (j < n) {
    const int tsrc = idx[b * T_ + j];
    const uint4* src = (const uint4*)(vh + ((size_t)b * T_ + tsrc) * D_ + h * 64 + cq);
    v0 = src[0]; v1 = src[1];
  }
  *(uint4*)&t[r][cq]     = v0;
  *(uint4*)&t[r][cq + 8] = v1;
  __syncthreads();

  f16 tmp[16];
#pragma unroll
  for (int xx = 0; xx < 16; ++xx) {
    int x = (xx + r) & 15;
    tmp[x] = t[cq + x][r];
  }
  f16* dst = vhT + ((size_t)bh * 64 + r) * T_ + tt * 64 + cq;
  *(uint4*)&dst[0] = *(uint4*)&tmp[0];
  *(uint4*)&dst[8] = *(uint4*)&tmp[8];
}

// ---------------------------------------------------------------------------
// Flash attention over COMPACTED keys (no mask ops). qh pre-scaled by
// SCALE*log2e -> P = exp2(S). Pad keys: kh=0 -> s=0 -> p=1; vh=0 -> PV+=0;
// corrected by lsum -= npad. S^T formulation (lane l16 = qrow for both S^T
// C-cols and PV A-rows); P round-trips wave-private LDS; l reduced once.
// ---------------------------------------------------------------------------
__global__ __launch_bounds__(256) void attn_mfma(
    const f16* __restrict__ qh, const f16* __restrict__ khc,
    const f16* __restrict__ vhT, const int* __restrict__ nkd,
    f16* __restrict__ oat) {
  __shared__ f16 Qs[64][72];
  __shared__ f16 Ks[64][72];     // [key][dh]
  __shared__ f16 Vt[64][72];     // [dh][key]
  __shared__ f16 Ps[4][16][72];  // per-wave [qrow(l16)][key]

  const int qt = blockIdx.x, bh = blockIdx.y;
  const int b = bh >> 4, h = bh & 15;
  const int tid = threadIdx.x;
  const int wave = tid >> 6, lane = tid & 63;
  const int quad = lane >> 4, l16 = lane & 15;
  const int sr = tid >> 2, sq = 16 * (tid & 3);

  const int n = nkd[b];
  const int nkt = (n + 63) >> 6;
  const int npad = (nkt << 6) - n;

  {  // stage Q once
    const uint4* src = (const uint4*)(qh + ((size_t)(b * T_ + qt * 64 + sr)) * D_ + h * 64 + sq);
    *(uint4*)&Qs[sr][sq]     = src[0];
    *(uint4*)&Qs[sr][sq + 8] = src[1];
  }
  __syncthreads();
  const f16x8 qf0 = *(const f16x8*)&Qs[wave * 16 + l16][quad * 8];
  const f16x8 qf1 = *(const f16x8*)&Qs[wave * 16 + l16][32 + quad * 8];

  float lsum = 0.f;
  f32x4 o[4] = {};

  const f16* kbase = khc + (size_t)b * T_ * D_ + h * 64;
  const f16* vbase = vhT + ((size_t)bh * 64 + sr) * T_;

  uint4 kr0, kr1, vr0, vr1;
  auto load_kv = [&](int kt) {
    const uint4* ks = (const uint4*)(kbase + (size_t)(kt * 64 + sr) * D_ + sq);
    kr0 = ks[0]; kr1 = ks[1];
    const uint4* vs = (const uint4*)(vbase + kt * 64 + sq);
    vr0 = vs[0]; vr1 = vs[1];
  };
  if (nkt > 0) load_kv(0);

  for (int kt = 0; kt < nkt; ++kt) {
    *(uint4*)&Ks[sr][sq]     = kr0;
    *(uint4*)&Ks[sr][sq + 8] = kr1;
    *(uint4*)&Vt[sr][sq]     = vr0;
    *(uint4*)&Vt[sr][sq + 8] = vr1;
    __syncthreads();
    if (kt + 1 < nkt) load_kv(kt + 1);  // prefetch next tile into regs

    // ---- S^T = K Q^T : D[m=key][n=qrow] ----
#pragma unroll
    for (int tn = 0; tn < 4; ++tn) {
      f16x8 kf0 = *(const f16x8*)&Ks[16 * tn + l16][quad * 8];
      f16x8 kf1 = *(const f16x8*)&Ks[16 * tn + l16][32 + quad * 8];
      f32x4 s = {0.f, 0.f, 0.f, 0.f};
      s = __builtin_amdgcn_mfma_f32_16x16x32_f16(kf0, qf0, s, 0, 0, 0);
      s = __builtin_amdgcn_mfma_f32_16x16x32_f16(kf1, qf1, s, 0, 0, 0);
      // lane holds S for qrow=l16, keys 16*tn + 4*quad + r
      float p0 = exp2f(s[0]);
      float p1 = exp2f(s[1]);
      float p2 = exp2f(s[2]);
      float p3 = exp2f(s[3]);
      lsum += (p0 + p1) + (p2 + p3);
      f16x4 pk;
      pk[0] = (f16)p0; pk[1] = (f16)p1; pk[2] = (f16)p2; pk[3] = (f16)p3;
      *(f16x4*)&Ps[wave][l16][16 * tn + 4 * quad] = pk;
    }

    // ---- O += P V ----
    f16x8 pf0 = *(const f16x8*)&Ps[wave][l16][quad * 8];
    f16x8 pf1 = *(const f16x8*)&Ps[wave][l16][32 + quad * 8];
#pragma unroll
    for (int t = 0; t < 4; ++t) {
      f16x8 vf0 = *(const f16x8*)&Vt[16 * t + l16][quad * 8];
      f16x8 vf1 = *(const f16x8*)&Vt[16 * t + l16][32 + quad * 8];
      o[t] = __builtin_amdgcn_mfma_f32_16x16x32_f16(pf0, vf0, o[t], 0, 0, 0);
      o[t] = __builtin_amdgcn_mfma_f32_16x16x32_f16(pf1, vf1, o[t], 0, 0, 0);
    }
    __syncthreads();
  }

  // total l per qrow=l16 (quads hold disjoint key subsets), minus pad keys
  lsum += __shfl_xor(lsum, 16);
  lsum += __shfl_xor(lsum, 32);
  lsum -= (float)npad;
  float inv[4];
#pragma unroll
  for (int r = 0; r < 4; ++r) inv[r] = 1.f / __shfl(lsum, 4 * quad + r);

  const size_t orow = (size_t)(b * T_ + qt * 64 + wave * 16 + 4 * quad);
#pragma unroll
  for (int r = 0; r < 4; ++r)
#pragma unroll
    for (int t = 0; t < 4; ++t)
      oat[(orow + r) * D_ + h * 64 + 16 * t + l16] = (f16)(o[t][r] * inv[r]);
}

// ---------------------------------------------------------------------------
extern "C" void kernel_launch(void* const* d_in, const int* in_sizes, int n_in,
                              void* d_out, int out_size, void* d_ws, size_t ws_size,
                              hipStream_t stream) {
  const float* q  = (const float*)d_in[0];
  const float* k  = (const float*)d_in[1];
  const float* v  = (const float*)d_in[2];
  const int* mask = (const int*)d_in[3];
  const float* Wq = (const float*)d_in[4];
  const float* bq = (const float*)d_in[5];
  const float* Wk = (const float*)d_in[6];
  const float* bk = (const float*)d_in[7];
  const float* Wv = (const float*)d_in[8];
  const float* bv = (const float*)d_in[9];
  const float* Wo = (const float*)d_in[10];
  const float* bo = (const float*)d_in[11];
  float* out = (float*)d_out;

  // ws layout (bytes), aliases annotated:
  //  0        xq (8MB)   -> vhT after QKV gemm
  //  8388608  xk (8MB)   -> oat after QKV gemm
  //  16777216 xv (8MB)   -> khc after QKV gemm
  //  25165824 Wt (8MB)
  //  33554432 bias (16KB)
  //  33570816 qkvh (24MB): qh | kh | vh
  //  58736640 idx (16KB)
  //  58753024 nk (8B)          total < 64MB (R1 proved >=64MB available)
  char* ws = (char*)d_ws;
  f16* xqkv  = (f16*)(ws);
  f16* Wt    = (f16*)(ws + 25165824);
  float* bsw = (float*)(ws + 33554432);
  f16* qkvh  = (f16*)(ws + 33570816);
  int* idx   = (int*)(ws + 58736640);
  int* nk    = (int*)(ws + 58753024);
  f16* vhT   = (f16*)(ws);
  f16* oat   = (f16*)(ws + 8388608);
  f16* khc   = (f16*)(ws + 16777216);

  const int M = B_ * T_;  // 4096
  dim3 blk(256);

  prep<<<dim3(7186), blk, 0, stream>>>(q, k, v, mask, Wq, Wk, Wv, Wo,
                                       bq, bk, bv, bo, xqkv, Wt, bsw, idx, nk);

  gemm_bt<128, f16><<<dim3(8, 32, 3), blk, 0, stream>>>(
      xqkv, Wt, bsw, qkvh, M, D_, D_, QSCALE);

  f16* qh = qkvh;
  f16* kh = qkvh + 4194304;
  f16* vh = qkvh + 8388608;

  kgather<<<dim3(32, 2), blk, 0, stream>>>(kh, idx, nk, khc);
  vtrans<<<dim3(32, 32), blk, 0, stream>>>(vh, idx, nk, vhT);

  attn_mfma<<<dim3(32, 32), blk, 0, stream>>>(qh, khc, vhT, nk, oat);

  gemm_bt<64, float><<<dim3(8, 64, 1), blk, 0, stream>>>(
      oat, Wt + 3145728, bsw + 3072, out, M, D_, D_, 1.f);
}

// Round 5
// 227.950 us; speedup vs baseline: 9.7368x; 1.0873x over previous
//
#include <hip/hip_runtime.h>
#include <hip/hip_bf16.h>
#include <math.h>

#define B_ 2
#define T_ 2048
#define D_ 1024
#define H_ 16
#define QSCALE (0.03125f * 1.44269504088896f)  // 1/sqrt(1024) * log2(e)

typedef _Float16 f16;
using f16x4 = __attribute__((ext_vector_type(4))) _Float16;
using f16x8 = __attribute__((ext_vector_type(8))) _Float16;
using f32x4 = __attribute__((ext_vector_type(4))) float;

__device__ __forceinline__ void gl16(const void* g, void* l) {
  __builtin_amdgcn_global_load_lds(
      (__attribute__((address_space(1))) void*)g,
      (__attribute__((address_space(3))) void*)l, 16, 0, 0);
}

// ---------------------------------------------------------------------------
// prep: fused cvt_x (0..6143) + cvt_w transpose (6144..7167) + pack_bias
// (7168..7183) + mask scan -> idx/inv/nk + khc pad-row zeroing (7184..7185)
// ---------------------------------------------------------------------------
__global__ __launch_bounds__(256) void prep(
    const float* __restrict__ q, const float* __restrict__ k,
    const float* __restrict__ v, const int* __restrict__ mask,
    const float* __restrict__ Wq, const float* __restrict__ Wk,
    const float* __restrict__ Wv, const float* __restrict__ Wo,
    const float* __restrict__ bq, const float* __restrict__ bk,
    const float* __restrict__ bv, const float* __restrict__ bo,
    f16* __restrict__ xqkv, f16* __restrict__ Wt, float* __restrict__ bias,
    int* __restrict__ idx, int* __restrict__ inv, int* __restrict__ nk,
    f16* __restrict__ khc) {
  __shared__ float sh[64][65];
  const int bid = blockIdx.x;
  const int tid = threadIdx.x;

  if (bid < 6144) {  // ---- cvt_x: fp32 -> f16 ----
    const int z = bid / 2048;
    const float* src = (z == 0) ? q : (z == 1) ? k : v;
    const size_t i = ((size_t)(bid % 2048) * 256 + tid) * 8;
    float4 a = *(const float4*)(src + i);
    float4 b = *(const float4*)(src + i + 4);
    f16x8 o;
    o[0] = (f16)a.x; o[1] = (f16)a.y; o[2] = (f16)a.z; o[3] = (f16)a.w;
    o[4] = (f16)b.x; o[5] = (f16)b.y; o[6] = (f16)b.z; o[7] = (f16)b.w;
    *(f16x8*)(xqkv + (size_t)z * 4194304 + i) = o;
  } else if (bid < 7168) {  // ---- cvt_w: W[K][N] fp32 -> Wt[N][K] f16 ----
    const int id = bid - 6144;
    const int z = id >> 8;
    const int k0 = ((id >> 4) & 15) * 64, n0 = (id & 15) * 64;
    const float* W = (z == 0) ? Wq : (z == 1) ? Wk : (z == 2) ? Wv : Wo;
    const int r = tid >> 2, c0 = (tid & 3) * 16;
#pragma unroll
    for (int i = 0; i < 4; ++i)
      *(float4*)&sh[r][c0 + 4 * i] =
          *(const float4*)&W[(size_t)(k0 + r) * 1024 + n0 + c0 + 4 * i];
    __syncthreads();
    f16 tmp[16];
#pragma unroll
    for (int i = 0; i < 16; ++i) tmp[i] = (f16)sh[c0 + i][r];
    f16* dst = Wt + (size_t)z * 1048576 + (size_t)(n0 + r) * 1024 + k0 + c0;
    *(f16x8*)dst = *(f16x8*)&tmp[0];
    *(f16x8*)(dst + 8) = *(f16x8*)&tmp[8];
  } else if (bid < 7184) {  // ---- pack_bias ----
    const int i = (bid - 7168) * 256 + tid;
    const int z = i >> 10;
    const float* s = (z == 0) ? bq : (z == 1) ? bk : (z == 2) ? bv : bo;
    bias[i] = s[i & 1023];
  } else {  // ---- mask scan + inverse map + khc pad zero, one block/batch ----
    const int b = bid - 7184;
    int* cnt = (int*)sh;
    int loc[8];
    int c = 0;
#pragma unroll
    for (int i = 0; i < 8; ++i) {
      loc[i] = mask[b * T_ + tid * 8 + i];
      c += loc[i];
    }
    cnt[tid] = c;
    __syncthreads();
    for (int off = 1; off < 256; off <<= 1) {
      int vsh = (tid >= off) ? cnt[tid - off] : 0;
      __syncthreads();
      cnt[tid] += vsh;
      __syncthreads();
    }
    int pos = cnt[tid] - c;  // exclusive prefix
#pragma unroll
    for (int i = 0; i < 8; ++i) {
      const int t = tid * 8 + i;
      if (loc[i]) {
        idx[b * T_ + pos] = t;
        inv[b * T_ + t] = pos;
        ++pos;
      } else {
        inv[b * T_ + t] = -1;
      }
    }
    const int n = cnt[255];
    if (tid == 255) nk[b] = n;
    // zero pad rows n..nkt*64-1 of khc (gemm writes only rows < n)
    const int nkt = (n + 63) >> 6;
    const int npadrows = (nkt << 6) - n;
    uint4 z4 = {0u, 0u, 0u, 0u};
    f16* base = khc + ((size_t)b * T_ + n) * D_;
    for (int i = tid; i < npadrows * 128; i += 256)
      *(uint4*)(base + (size_t)i * 8) = z4;
  }
}

// ---------------------------------------------------------------------------
// m97-style GEMM: C[M,N] = X[M,K] @ Wt[N,K]^T + bias, f16 in.
// TM x 128 tile, BK=32, global_load_lds width-16 staging, 4 waves (2x2).
// z selects (X slice, Wt slice, bias slice, C pointer). z==0 applies qscale.
// z==1 with inv != nullptr: scatter rows through inv (K compaction), masked
// rows dropped (pad rows pre-zeroed by prep).
// ---------------------------------------------------------------------------
template <int TM, typename OT>
__global__ __launch_bounds__(256) void gemm_bt(
    const f16* __restrict__ Xb, const f16* __restrict__ Wtb,
    const float* __restrict__ biasb, void* __restrict__ C0,
    void* __restrict__ C1, void* __restrict__ C2,
    const int* __restrict__ inv, int M, int N, int K, float qscale) {
  constexpr int FM = TM / 32;
  __shared__ __align__(16) f16 As[TM * 32];
  __shared__ __align__(16) f16 Bs[128 * 32];
  const int z = blockIdx.z;
  const f16* X  = Xb  + (size_t)z * M * K;
  const f16* Wt = Wtb + (size_t)z * N * K;
  const float* bias = biasb + (size_t)z * N;
  OT* C = (OT*)((z == 0) ? C0 : (z == 1) ? C1 : C2);
  const float scl = (z == 0) ? qscale : 1.f;

  const int tid = threadIdx.x;
  const int wave = tid >> 6, lane = tid & 63;
  const int quad = lane >> 4, l16 = lane & 15;
  const int wm = wave & 1, wn = wave >> 1;
  const int m0 = blockIdx.y * TM, n0 = blockIdx.x * 128;

  f32x4 acc[FM][4] = {};

  const f16* asrc = X  + (size_t)(m0 + (tid >> 2)) * K + (tid & 3) * 8;
  const f16* bsrc = Wt + (size_t)(n0 + (tid >> 2)) * K + (tid & 3) * 8;
  char* aldst = (char*)As + tid * 16;
  char* bldst = (char*)Bs + tid * 16;
  const size_t rstep = (size_t)64 * K;

  const int NK = K >> 5;
  for (int kt = 0; kt < NK; ++kt) {
    if (kt) __syncthreads();
    gl16(asrc, aldst);
    if constexpr (TM == 128) gl16(asrc + rstep, aldst + 4096);
    gl16(bsrc, bldst);
    gl16(bsrc + rstep, bldst + 4096);
    asrc += 32; bsrc += 32;
    __syncthreads();

    f16x8 af[FM], bf[4];
#pragma unroll
    for (int t = 0; t < FM; ++t)
      af[t] = *(const f16x8*)&As[((TM / 2) * wm + 16 * t + l16) * 32 + quad * 8];
#pragma unroll
    for (int t = 0; t < 4; ++t)
      bf[t] = *(const f16x8*)&Bs[(64 * wn + 16 * t + l16) * 32 + quad * 8];
#pragma unroll
    for (int i = 0; i < FM; ++i)
#pragma unroll
      for (int j = 0; j < 4; ++j)
        acc[i][j] = __builtin_amdgcn_mfma_f32_16x16x32_f16(af[i], bf[j], acc[i][j], 0, 0, 0);
  }

  const int cm = m0 + (TM / 2) * wm + 4 * quad;
  const int cn = n0 + 64 * wn + l16;
  float bv[4];
#pragma unroll
  for (int tn = 0; tn < 4; ++tn) bv[tn] = bias[cn + 16 * tn];

  if (inv != nullptr && z == 1) {  // K-compaction scatter
    const int bb = m0 >> 11;
#pragma unroll
    for (int tm = 0; tm < FM; ++tm) {
#pragma unroll
      for (int r = 0; r < 4; ++r) {
        const int m = cm + 16 * tm + r;
        const int j = inv[m];
        if (j >= 0) {
          OT* row = C + ((size_t)(bb << 11) + j) * N;
#pragma unroll
          for (int tn = 0; tn < 4; ++tn)
            row[cn + 16 * tn] = (OT)(acc[tm][tn][r] + bv[tn]);
        }
      }
    }
  } else {
#pragma unroll
    for (int tm = 0; tm < FM; ++tm)
#pragma unroll
      for (int r = 0; r < 4; ++r) {
        OT* row = C + (size_t)(cm + 16 * tm + r) * N;
#pragma unroll
        for (int tn = 0; tn < 4; ++tn)
          row[cn + 16 * tn] = (OT)((acc[tm][tn][r] + bv[tn]) * scl);
      }
  }
}

// ---------------------------------------------------------------------------
// vtrans: gather + transpose V. vhT[bh][dh][j] = vh[b][idx[j]][h*64+dh],
// zeros for pad j; tiles >= nkt untouched (attn never reads them).
// ---------------------------------------------------------------------------
__global__ __launch_bounds__(256) void vtrans(
    const f16* __restrict__ vh, const int* __restrict__ idx,
    const int* __restrict__ nk, f16* __restrict__ vhT) {
  const int tt = blockIdx.x, bh = blockIdx.y;
  const int b = bh >> 4, h = bh & 15;
  const int n = nk[b];
  const int nkt = (n + 63) >> 6;
  if (tt >= nkt) return;
  __shared__ f16 t[64][72];
  const int tid = threadIdx.x;
  const int r = tid >> 2, cq = 16 * (tid & 3);

  const int j = tt * 64 + r;
  uint4 v0 = {0u, 0u, 0u, 0u}, v1 = {0u, 0u, 0u, 0u};
  if (j < n) {
    const int tsrc = idx[b * T_ + j];
    const uint4* src = (const uint4*)(vh + ((size_t)b * T_ + tsrc) * D_ + h * 64 + cq);
    v0 = src[0]; v1 = src[1];
  }
  *(uint4*)&t[r][cq]     = v0;
  *(uint4*)&t[r][cq + 8] = v1;
  __syncthreads();

  f16 tmp[16];
#pragma unroll
  for (int xx = 0; xx < 16; ++xx) {
    int x = (xx + r) & 15;
    tmp[x] = t[cq + x][r];
  }
  f16* dst = vhT + ((size_t)bh * 64 + r) * T_ + tt * 64 + cq;
  *(uint4*)&dst[0] = *(uint4*)&tmp[0];
  *(uint4*)&dst[8] = *(uint4*)&tmp[8];
}

// ---------------------------------------------------------------------------
// Flash attention over compacted keys. Block = 128 q-rows (grid 16 x 32);
// wave owns 32 q-rows (2 l16-groups) -> K/V LDS frag reads amortized over 2x
// MFMAs vs R4. Q frags direct from global, cached in regs (no Qs LDS).
// qh pre-scaled by SCALE*log2e -> P = exp2(S); pad keys contribute p=1,
// corrected via lsum -= npad. P round-trips wave-private LDS strip.
// ---------------------------------------------------------------------------
__global__ __launch_bounds__(256) void attn_mfma(
    const f16* __restrict__ qh, const f16* __restrict__ khc,
    const f16* __restrict__ vhT, const int* __restrict__ nkd,
    f16* __restrict__ oat) {
  __shared__ f16 Ks[64][72];     // [key][dh]
  __shared__ f16 Vt[64][72];     // [dh][key]
  __shared__ f16 Ps[4][32][72];  // per-wave [qrow][key]

  const int qt = blockIdx.x, bh = blockIdx.y;
  const int b = bh >> 4, h = bh & 15;
  const int tid = threadIdx.x;
  const int wave = tid >> 6, lane = tid & 63;
  const int quad = lane >> 4, l16 = lane & 15;
  const int sr = tid >> 2, sq = 16 * (tid & 3);

  const int n = nkd[b];
  const int nkt = (n + 63) >> 6;
  const int npad = (nkt << 6) - n;

  // Q fragments direct from global: rows qt*128 + wave*32 + 16*gq + l16
  f16x8 qf[2][2];
#pragma unroll
  for (int gq = 0; gq < 2; ++gq) {
    const f16* qp = qh + ((size_t)(b * T_ + qt * 128 + wave * 32 + 16 * gq + l16)) * D_ + h * 64 + quad * 8;
    qf[gq][0] = *(const f16x8*)qp;
    qf[gq][1] = *(const f16x8*)(qp + 32);
  }

  float lsum[2] = {0.f, 0.f};
  f32x4 o[2][4] = {};

  const f16* kbase = khc + (size_t)b * T_ * D_ + h * 64;
  const f16* vbase = vhT + ((size_t)bh * 64 + sr) * T_;

  uint4 kr0, kr1, vr0, vr1;
  auto load_kv = [&](int kt) {
    const uint4* ks = (const uint4*)(kbase + (size_t)(kt * 64 + sr) * D_ + sq);
    kr0 = ks[0]; kr1 = ks[1];
    const uint4* vs = (const uint4*)(vbase + kt * 64 + sq);
    vr0 = vs[0]; vr1 = vs[1];
  };
  if (nkt > 0) load_kv(0);

  for (int kt = 0; kt < nkt; ++kt) {
    *(uint4*)&Ks[sr][sq]     = kr0;
    *(uint4*)&Ks[sr][sq + 8] = kr1;
    *(uint4*)&Vt[sr][sq]     = vr0;
    *(uint4*)&Vt[sr][sq + 8] = vr1;
    __syncthreads();
    if (kt + 1 < nkt) load_kv(kt + 1);  // prefetch next tile into regs

    // ---- S^T = K Q^T : D[m=key][n=qrow], K frags shared across q-groups ----
#pragma unroll
    for (int tn = 0; tn < 4; ++tn) {
      f16x8 kf0 = *(const f16x8*)&Ks[16 * tn + l16][quad * 8];
      f16x8 kf1 = *(const f16x8*)&Ks[16 * tn + l16][32 + quad * 8];
#pragma unroll
      for (int gq = 0; gq < 2; ++gq) {
        f32x4 s = {0.f, 0.f, 0.f, 0.f};
        s = __builtin_amdgcn_mfma_f32_16x16x32_f16(kf0, qf[gq][0], s, 0, 0, 0);
        s = __builtin_amdgcn_mfma_f32_16x16x32_f16(kf1, qf[gq][1], s, 0, 0, 0);
        float p0 = exp2f(s[0]), p1 = exp2f(s[1]);
        float p2 = exp2f(s[2]), p3 = exp2f(s[3]);
        lsum[gq] += (p0 + p1) + (p2 + p3);
        f16x4 pk;
        pk[0] = (f16)p0; pk[1] = (f16)p1; pk[2] = (f16)p2; pk[3] = (f16)p3;
        *(f16x4*)&Ps[wave][16 * gq + l16][16 * tn + 4 * quad] = pk;
      }
    }

    // ---- O += P V, V frags shared across q-groups ----
    f16x8 pf[2][2];
#pragma unroll
    for (int gq = 0; gq < 2; ++gq) {
      pf[gq][0] = *(const f16x8*)&Ps[wave][16 * gq + l16][quad * 8];
      pf[gq][1] = *(const f16x8*)&Ps[wave][16 * gq + l16][32 + quad * 8];
    }
#pragma unroll
    for (int t = 0; t < 4; ++t) {
      f16x8 vf0 = *(const f16x8*)&Vt[16 * t + l16][quad * 8];
      f16x8 vf1 = *(const f16x8*)&Vt[16 * t + l16][32 + quad * 8];
#pragma unroll
      for (int gq = 0; gq < 2; ++gq) {
        o[gq][t] = __builtin_amdgcn_mfma_f32_16x16x32_f16(pf[gq][0], vf0, o[gq][t], 0, 0, 0);
        o[gq][t] = __builtin_amdgcn_mfma_f32_16x16x32_f16(pf[gq][1], vf1, o[gq][t], 0, 0, 0);
      }
    }
    __syncthreads();
  }

#pragma unroll
  for (int gq = 0; gq < 2; ++gq) {
    float ls = lsum[gq];
    ls += __shfl_xor(ls, 16);   // quads hold disjoint key subsets
    ls += __shfl_xor(ls, 32);
    ls -= (float)npad;
    const size_t orow = (size_t)(b * T_ + qt * 128 + wave * 32 + 16 * gq + 4 * quad);
#pragma unroll
    for (int r = 0; r < 4; ++r) {
      const float iv = 1.f / __shfl(ls, 4 * quad + r);
#pragma unroll
      for (int t = 0; t < 4; ++t)
        oat[(orow + r) * D_ + h * 64 + 16 * t + l16] = (f16)(o[gq][t][r] * iv);
    }
  }
}

// ---------------------------------------------------------------------------
extern "C" void kernel_launch(void* const* d_in, const int* in_sizes, int n_in,
                              void* d_out, int out_size, void* d_ws, size_t ws_size,
                              hipStream_t stream) {
  const float* q  = (const float*)d_in[0];
  const float* k  = (const float*)d_in[1];
  const float* v  = (const float*)d_in[2];
  const int* mask = (const int*)d_in[3];
  const float* Wq = (const float*)d_in[4];
  const float* bq = (const float*)d_in[5];
  const float* Wk = (const float*)d_in[6];
  const float* bk = (const float*)d_in[7];
  const float* Wv = (const float*)d_in[8];
  const float* bv = (const float*)d_in[9];
  const float* Wo = (const float*)d_in[10];
  const float* bo = (const float*)d_in[11];
  float* out = (float*)d_out;

  // ws layout (bytes):
  //  0        xq (8MB)  -> vhT after gemm_qkv
  //  8388608  xk (8MB)  -> oat after gemm_qkv
  //  16777216 xv (8MB)
  //  25165824 Wt (8MB)
  //  33554432 qh (8MB)
  //  41943040 vh (8MB)
  //  50331648 khc (8MB)
  //  58720256 bias(16KB) | idx(16KB) | inv(16KB) | nk(8B)
  char* ws = (char*)d_ws;
  f16* xqkv  = (f16*)(ws);
  f16* Wt    = (f16*)(ws + 25165824);
  f16* qh    = (f16*)(ws + 33554432);
  f16* vh    = (f16*)(ws + 41943040);
  f16* khc   = (f16*)(ws + 50331648);
  float* bsw = (float*)(ws + 58720256);
  int* idx   = (int*)(ws + 58736640);
  int* inv   = (int*)(ws + 58753024);
  int* nk    = (int*)(ws + 58769408);
  f16* vhT   = (f16*)(ws);             // aliases xq (dead after gemm_qkv)
  f16* oat   = (f16*)(ws + 8388608);   // aliases xk (dead after gemm_qkv)

  const int M = B_ * T_;  // 4096
  dim3 blk(256);

  prep<<<dim3(7186), blk, 0, stream>>>(q, k, v, mask, Wq, Wk, Wv, Wo,
                                       bq, bk, bv, bo, xqkv, Wt, bsw,
                                       idx, inv, nk, khc);

  gemm_bt<128, f16><<<dim3(8, 32, 3), blk, 0, stream>>>(
      xqkv, Wt, bsw, qh, khc, vh, inv, M, D_, D_, QSCALE);

  vtrans<<<dim3(32, 32), blk, 0, stream>>>(vh, idx, nk, vhT);

  attn_mfma<<<dim3(16, 32), blk, 0, stream>>>(qh, khc, vhT, nk, oat);

  gemm_bt<64, float><<<dim3(8, 64, 1), blk, 0, stream>>>(
      oat, Wt + 3145728, bsw + 3072, out, out, out, nullptr, M, D_, D_, 1.f);
}